// Round 8
// baseline (2129.155 us; speedup 1.0000x reference)
//
#include <hip/hip_runtime.h>
#include <stdint.h>

#define THREADS 256
#define BR      96

// d_ws layout: bf16 weights as MFMA A-fragments, CONTIGUOUS per wave (ng).
// Per-ng stream (200KB): [layer0: 8KB][layer1..6: 32KB each].
// Fragment = 1KB: lane (hi*32+l31) holds n = base_n + l31, k = kk*16 + hi*8 + e.
// Within a layer, frag index = (c*4+kk)*2 + ft  (ft = which 32-neuron half).
#define NG_STRIDE 204800
#define WS_WOUT   819200                 // layer7: 16 kk x 1 frag = 16KB
#define WS_TOTAL  (WS_WOUT + 16384)

typedef short bf16x8 __attribute__((ext_vector_type(8)));
typedef short bf16x4 __attribute__((ext_vector_type(4)));
typedef float f32x16 __attribute__((ext_vector_type(16)));
typedef float f32x4v __attribute__((ext_vector_type(4)));

__device__ __forceinline__ unsigned short f2bf(float f) {
    union { float f; unsigned int u; } v; v.f = f;
    unsigned int u = v.u;
    u += 0x7fffu + ((u >> 16) & 1u);   // round-to-nearest-even
    return (unsigned short)(u >> 16);
}
__device__ __forceinline__ unsigned int cvt_pk_bf16(float lo, float hi) {
    unsigned int d;
    asm("v_cvt_pk_bf16_f32 %0, %1, %2" : "=v"(d) : "v"(lo), "v"(hi));
    return d;
}
// act LDS swizzle: byte offset o of row r stored at o ^ ((r&15)<<3).
// 8B-granular -> read as 2x ds_read_b64: 32 lanes spread over 16 bank-pairs
// (2-way aliasing = free, m136) instead of b128's structural 4-way.
__device__ __forceinline__ bf16x8 ld_act(const unsigned char* lo,
                                         const unsigned char* hi) {
    bf16x4 a = *(const bf16x4*)lo;
    bf16x4 b = *(const bf16x4*)hi;
    return __builtin_shufflevector(a, b, 0, 1, 2, 3, 4, 5, 6, 7);
}

// ---------------------------------------------------------------------------
// prep: fp32 weights -> bf16 MFMA A-fragment streams in ws (same as R3/R5/R7)
// ---------------------------------------------------------------------------
__global__ void prep_kernel(const float* __restrict__ W_in,
                            const float* __restrict__ W_hid,
                            const float* __restrict__ W_out,
                            unsigned char* __restrict__ ws) {
    int id = blockIdx.x * 256 + threadIdx.x;
    if (id < 16384) {                        // W_in: k(64 pad) x n(256)
        int n = id & 255, k = id >> 8;
        int ng = n >> 6, ft = (n >> 5) & 1, ln = n & 31;
        int kk = k >> 4, hi = (k >> 3) & 1, e = k & 7;
        float v = (k < 40) ? W_in[k * 256 + n] : 0.f;
        *(unsigned short*)(ws + ng * NG_STRIDE + (kk * 2 + ft) * 1024
                           + (hi * 32 + ln) * 16 + e * 2) = f2bf(v);
    } else if (id < 16384 + 393216) {        // W_hid: 6 x k(256) x n(256)
        int e2 = id - 16384;
        int l = e2 >> 16, r = e2 & 65535;
        int k = r >> 8, n = r & 255;
        int c = k >> 6, kk = (k >> 4) & 3, hi = (k >> 3) & 1, e = k & 7;
        int ng = n >> 6, ft = (n >> 5) & 1, ln = n & 31;
        float v = W_hid[l * 65536 + k * 256 + n];
        *(unsigned short*)(ws + ng * NG_STRIDE + 8192 + l * 32768
                           + ((c * 4 + kk) * 2 + ft) * 1024
                           + (hi * 32 + ln) * 16 + e * 2) = f2bf(v);
    } else if (id < 16384 + 393216 + 8192) { // W_out: k(256) x n(3 -> 32 pad)
        int e3 = id - 16384 - 393216;
        int n = e3 >> 8, k = e3 & 255;
        int kk = k >> 4, hi = (k >> 3) & 1, e = k & 7;
        float v = (n < 3) ? W_out[k * 3 + n] : 0.f;
        *(unsigned short*)(ws + WS_WOUT + kk * 1024
                           + (hi * 32 + n) * 16 + e * 2) = f2bf(v);
    }
}

// ---------------------------------------------------------------------------
// one layer: wave = 64n x 96r. A from global, B from LDS (2x b64, swizzled,
// precomputed addresses), compiler-scheduled (R5/R7-proven body structure).
// ---------------------------------------------------------------------------
template <int NC>
__device__ __forceinline__ void layer_pass(const unsigned char* __restrict__ wl,
                                           const float* __restrict__ bp,
                                           unsigned char* actL, f32x16 (&acc)[2][3],
                                           const unsigned char* const (&alo)[4],
                                           const unsigned char* const (&ahi)[4],
                                           int nblk, int l31,
                                           int hi, int rswz) {
    // bias -> accumulator init (C/D layout: n = (reg&3) + 8*(reg>>2) + 4*hi)
    #pragma unroll
    for (int tn = 0; tn < 2; ++tn) {
        #pragma unroll
        for (int g4 = 0; g4 < 4; ++g4) {
            f32x4v bv = *(const f32x4v*)(bp + nblk + tn * 32 + g4 * 8 + hi * 4);
            #pragma unroll
            for (int tr = 0; tr < 3; ++tr) {
                #pragma unroll
                for (int j = 0; j < 4; ++j)
                    acc[tn][tr][g4 * 4 + j] = bv[j];
            }
        }
    }

    __builtin_amdgcn_s_setprio(1);
    #pragma unroll
    for (int c = 0; c < NC; ++c) {
        #pragma unroll
        for (int kk = 0; kk < 4; ++kk) {
            const unsigned char* fp = wl + (c * 4 + kk) * 2048;
            bf16x8 a0 = *(const bf16x8*)(fp);
            bf16x8 a1 = *(const bf16x8*)(fp + 1024);
            const int cb = c * 128;          // folds into ds_read immediate
            bf16x8 b0 = ld_act(alo[kk] + cb,          ahi[kk] + cb);
            bf16x8 b1 = ld_act(alo[kk] + 16384 + cb,  ahi[kk] + 16384 + cb);
            bf16x8 b2 = ld_act(alo[kk] + 32768 + cb,  ahi[kk] + 32768 + cb);
            acc[0][0] = __builtin_amdgcn_mfma_f32_32x32x16_bf16(a0, b0, acc[0][0], 0, 0, 0);
            acc[1][0] = __builtin_amdgcn_mfma_f32_32x32x16_bf16(a1, b0, acc[1][0], 0, 0, 0);
            acc[0][1] = __builtin_amdgcn_mfma_f32_32x32x16_bf16(a0, b1, acc[0][1], 0, 0, 0);
            acc[1][1] = __builtin_amdgcn_mfma_f32_32x32x16_bf16(a1, b1, acc[1][1], 0, 0, 0);
            acc[0][2] = __builtin_amdgcn_mfma_f32_32x32x16_bf16(a0, b2, acc[0][2], 0, 0, 0);
            acc[1][2] = __builtin_amdgcn_mfma_f32_32x32x16_bf16(a1, b2, acc[1][2], 0, 0, 0);
        }
    }
    __builtin_amdgcn_s_setprio(0);

    __syncthreads();   // all waves done READING act
    #pragma unroll
    for (int tr = 0; tr < 3; ++tr) {
        unsigned char* rowp = actL + (tr * 32 + l31) * 512;
        #pragma unroll
        for (int tn = 0; tn < 2; ++tn) {
            #pragma unroll
            for (int g4 = 0; g4 < 4; ++g4) {
                float v0 = fmaxf(acc[tn][tr][g4 * 4 + 0], 0.f);
                float v1 = fmaxf(acc[tn][tr][g4 * 4 + 1], 0.f);
                float v2 = fmaxf(acc[tn][tr][g4 * 4 + 2], 0.f);
                float v3 = fmaxf(acc[tn][tr][g4 * 4 + 3], 0.f);
                int n0b = (nblk + tn * 32 + g4 * 8 + hi * 4) * 2;
                uint2 u; u.x = cvt_pk_bf16(v0, v1); u.y = cvt_pk_bf16(v2, v3);
                *(uint2*)(rowp + (n0b ^ rswz)) = u;
            }
        }
    }
    __syncthreads();   // act ready for next layer
}

// ---------------------------------------------------------------------------
// fused MLP: enc -> 7x(GEMM+bias+relu), act in LDS, weights global->reg
// 96 rows/block, 3 blocks/CU (TLP: 3 waves/SIMD hides epilogue+barriers)
// ---------------------------------------------------------------------------
__global__ __launch_bounds__(THREADS, 3)
void nerf_main(const float* __restrict__ x,
               const float* __restrict__ b_in,
               const float* __restrict__ b_hid,
               const float* __restrict__ b_out,
               const unsigned char* __restrict__ ws,
               float* __restrict__ out, long ntot) {
    __shared__ __align__(16) unsigned char actL[49152];  // bf16 [96][256]

    const int tid  = threadIdx.x;
    const int lane = tid & 63;
    const int wv   = tid >> 6;            // 0..3 (= ng)
    const int l31  = lane & 31;
    const int hi   = lane >> 5;
    const int hi16 = hi << 4;
    const int rswz  = (l31 & 15) << 3;    // 8B-granular act swizzle
    const int rswz2 = rswz ^ 8;
    const int nblk = wv * 64;
    const long gr0 = (long)blockIdx.x * BR;

    // ---- positional encoding (R7 body + tail guards) ----
    #pragma unroll
    for (int pass = 0; pass < 2; ++pass) {
        const int rr = (tid >> 2) + pass * 64;   // 0..127
        if (rr < BR) {
            const int part = tid & 3;
            const int co = part >> 1, hf = part & 1;
            const long grow = gr0 + rr;
            float xv = (grow < ntot) ? x[grow * 2 + co] : 0.f;
            unsigned char* rowp = actL + rr * 512;
            const int rsw = (rr & 15) << 3;
            const int kb = co * 20 + hf * 10;
            float vv[10];
            #pragma unroll
            for (int f = 0; f < 10; ++f) {
                float ang = xv * (float)(1 << f);
                vv[f] = hf ? __cosf(ang) : __sinf(ang);
            }
            #pragma unroll
            for (int p = 0; p < 5; ++p) {
                unsigned int u = cvt_pk_bf16(vv[2 * p], vv[2 * p + 1]);
                int byte = (kb + 2 * p) * 2;
                *(unsigned int*)(rowp + (byte ^ rsw)) = u;
            }
            int z = 80 + part * 12;           // zero-pad bytes [80,128)
            *(unsigned int*)(rowp + ((z    ) ^ rsw)) = 0u;
            *(unsigned int*)(rowp + ((z + 4) ^ rsw)) = 0u;
            *(unsigned int*)(rowp + ((z + 8) ^ rsw)) = 0u;
        }
    }
    __syncthreads();

    // precomputed swizzled B-read addresses (kills per-read VALU)
    const unsigned char* alo[4];
    const unsigned char* ahi[4];
    #pragma unroll
    for (int kk = 0; kk < 4; ++kk) {
        const int bo = kk * 32 + hi16;
        alo[kk] = actL + l31 * 512 + (bo ^ rswz);
        ahi[kk] = actL + l31 * 512 + (bo ^ rswz2);
    }

    f32x16 acc[2][3];
    const unsigned char* wstream = ws + wv * NG_STRIDE + lane * 16;

    // layer 0 (k=64, 1 chunk)
    layer_pass<1>(wstream, b_in, actL, acc, alo, ahi, nblk, l31, hi, rswz);
    wstream += 8192;

    // layers 1..6
    #pragma unroll 1
    for (int l = 0; l < 6; ++l) {
        layer_pass<4>(wstream, b_hid + l * 256,
                      actL, acc, alo, ahi, nblk, l31, hi, rswz);
        wstream += 32768;
    }

    // ---- layer 7: [96][256] @ Wt_out[32pad][256] -> tanh/100 -> out ----
    if (wv < 3) {
        f32x16 c0, c1;
        #pragma unroll
        for (int j = 0; j < 16; ++j) { c0[j] = 0.f; c1[j] = 0.f; }
        const unsigned char* wo   = ws + WS_WOUT + lane * 16;
        const unsigned char* arow = actL + (wv * 32 + l31) * 512;
        #pragma unroll
        for (int kk = 0; kk < 16; ++kk) {
            bf16x8 a = *(const bf16x8*)(wo + kk * 1024);
            const int bo = kk * 32 + hi16;
            bf16x8 b = ld_act(arow + (bo ^ rswz), arow + (bo ^ rswz2));
            if (kk & 1) c1 = __builtin_amdgcn_mfma_f32_32x32x16_bf16(a, b, c1, 0, 0, 0);
            else        c0 = __builtin_amdgcn_mfma_f32_32x32x16_bf16(a, b, c0, 0, 0, 0);
        }
        if (hi == 0) {
            long row = gr0 + wv * 32 + l31;
            if (row < ntot) {
                float* op = out + row * 3;
                #pragma unroll
                for (int j = 0; j < 3; ++j)
                    op[j] = tanhf(c0[j] + c1[j] + b_out[j]) * 0.01f;
            }
        }
    }
}

extern "C" void kernel_launch(void* const* d_in, const int* in_sizes, int n_in,
                              void* d_out, int out_size, void* d_ws, size_t ws_size,
                              hipStream_t stream) {
    (void)n_in; (void)out_size;
    const float* x     = (const float*)d_in[0];
    const float* W_in  = (const float*)d_in[1];
    const float* b_in  = (const float*)d_in[2];
    const float* W_hid = (const float*)d_in[3];
    const float* b_hid = (const float*)d_in[4];
    const float* W_out = (const float*)d_in[5];
    const float* b_out = (const float*)d_in[6];
    unsigned char* ws  = (unsigned char*)d_ws;
    float* out = (float*)d_out;

    if (ws_size < (size_t)WS_TOTAL) return;

    const long ntot = (long)in_sizes[0] / 2;          // total points
    const int  grid = (int)((ntot + BR - 1) / BR);

    prep_kernel<<<1632, 256, 0, stream>>>(W_in, W_hid, W_out, ws);
    nerf_main<<<grid, THREADS, 0, stream>>>(x, b_in, b_hid, b_out, ws, out, ntot);
}

// Round 9
// 2077.937 us; speedup vs baseline: 1.0246x; 1.0246x over previous
//
#include <hip/hip_runtime.h>
#include <stdint.h>

#define THREADS 512
#define BR      128

// d_ws layout: bf16 weights as MFMA A-fragments, CONTIGUOUS per wave (ng).
// Per-ng stream (200KB): [layer0: 8KB][layer1..6: 32KB each].
// Fragment = 1KB: lane (hi*32+l31) holds n = base_n + l31, k = kk*16 + hi*8 + e.
// Within a layer, frag index = (c*4+kk)*2 + ft  (ft = which 32-neuron half).
#define NG_STRIDE 204800
#define WS_WOUT   819200                 // layer7: 16 kk x 1 frag = 16KB
#define WS_TOTAL  (WS_WOUT + 16384)

typedef short bf16x8 __attribute__((ext_vector_type(8)));
typedef short bf16x4 __attribute__((ext_vector_type(4)));
typedef float f32x16 __attribute__((ext_vector_type(16)));
typedef float f32x4v __attribute__((ext_vector_type(4)));

__device__ __forceinline__ unsigned short f2bf(float f) {
    union { float f; unsigned int u; } v; v.f = f;
    unsigned int u = v.u;
    u += 0x7fffu + ((u >> 16) & 1u);   // round-to-nearest-even
    return (unsigned short)(u >> 16);
}
__device__ __forceinline__ unsigned int cvt_pk_bf16(float lo, float hi) {
    unsigned int d;
    asm("v_cvt_pk_bf16_f32 %0, %1, %2" : "=v"(d) : "v"(lo), "v"(hi));
    return d;
}
// act LDS swizzle: byte offset o of row r stored at o ^ ((r&15)<<3).
// 8B-granular -> read as 2x ds_read_b64: 32 lanes spread over 16 bank-pairs
// (2-way aliasing = free, m136) instead of b128's structural 4-way.
__device__ __forceinline__ bf16x8 ld_act(const unsigned char* lo,
                                         const unsigned char* hi) {
    bf16x4 a = *(const bf16x4*)lo;
    bf16x4 b = *(const bf16x4*)hi;
    return __builtin_shufflevector(a, b, 0, 1, 2, 3, 4, 5, 6, 7);
}

// ---------------------------------------------------------------------------
// prep: fp32 weights -> bf16 MFMA A-fragment streams in ws (same as R3/R5/R7)
// ---------------------------------------------------------------------------
__global__ void prep_kernel(const float* __restrict__ W_in,
                            const float* __restrict__ W_hid,
                            const float* __restrict__ W_out,
                            unsigned char* __restrict__ ws) {
    int id = blockIdx.x * 256 + threadIdx.x;
    if (id < 16384) {                        // W_in: k(64 pad) x n(256)
        int n = id & 255, k = id >> 8;
        int ng = n >> 6, ft = (n >> 5) & 1, ln = n & 31;
        int kk = k >> 4, hi = (k >> 3) & 1, e = k & 7;
        float v = (k < 40) ? W_in[k * 256 + n] : 0.f;
        *(unsigned short*)(ws + ng * NG_STRIDE + (kk * 2 + ft) * 1024
                           + (hi * 32 + ln) * 16 + e * 2) = f2bf(v);
    } else if (id < 16384 + 393216) {        // W_hid: 6 x k(256) x n(256)
        int e2 = id - 16384;
        int l = e2 >> 16, r = e2 & 65535;
        int k = r >> 8, n = r & 255;
        int c = k >> 6, kk = (k >> 4) & 3, hi = (k >> 3) & 1, e = k & 7;
        int ng = n >> 6, ft = (n >> 5) & 1, ln = n & 31;
        float v = W_hid[l * 65536 + k * 256 + n];
        *(unsigned short*)(ws + ng * NG_STRIDE + 8192 + l * 32768
                           + ((c * 4 + kk) * 2 + ft) * 1024
                           + (hi * 32 + ln) * 16 + e * 2) = f2bf(v);
    } else if (id < 16384 + 393216 + 8192) { // W_out: k(256) x n(3 -> 32 pad)
        int e3 = id - 16384 - 393216;
        int n = e3 >> 8, k = e3 & 255;
        int kk = k >> 4, hi = (k >> 3) & 1, e = k & 7;
        float v = (n < 3) ? W_out[k * 3 + n] : 0.f;
        *(unsigned short*)(ws + WS_WOUT + kk * 1024
                           + (hi * 32 + n) * 16 + e * 2) = f2bf(v);
    }
}

// ---------------------------------------------------------------------------
// one layer: wave = 64n x 64r (R2-proven tiling that fits 4 waves/SIMD).
// A from global stream, B from LDS (2x b64, swizzled, precomputed addrs).
// ---------------------------------------------------------------------------
template <int NC>
__device__ __forceinline__ void layer_pass(const unsigned char* __restrict__ wl,
                                           const float* __restrict__ bp,
                                           unsigned char* actL, f32x16 (&acc)[2][2],
                                           const unsigned char* const (&alo)[4],
                                           const unsigned char* const (&ahi)[4],
                                           int nblk, int rbase, int l31,
                                           int hi, int rswz) {
    // bias -> accumulator init (C/D layout: n = (reg&3) + 8*(reg>>2) + 4*hi)
    #pragma unroll
    for (int tn = 0; tn < 2; ++tn) {
        #pragma unroll
        for (int g4 = 0; g4 < 4; ++g4) {
            f32x4v bv = *(const f32x4v*)(bp + nblk + tn * 32 + g4 * 8 + hi * 4);
            #pragma unroll
            for (int tr = 0; tr < 2; ++tr) {
                #pragma unroll
                for (int j = 0; j < 4; ++j)
                    acc[tn][tr][g4 * 4 + j] = bv[j];
            }
        }
    }

    __builtin_amdgcn_s_setprio(1);
    #pragma unroll
    for (int c = 0; c < NC; ++c) {
        #pragma unroll
        for (int kk = 0; kk < 4; ++kk) {
            const unsigned char* fp = wl + (c * 4 + kk) * 2048;
            bf16x8 a0 = *(const bf16x8*)(fp);
            bf16x8 a1 = *(const bf16x8*)(fp + 1024);
            const int cb = c * 128;          // folds into ds_read immediate
            bf16x8 b0 = ld_act(alo[kk] + cb,          ahi[kk] + cb);
            bf16x8 b1 = ld_act(alo[kk] + 16384 + cb,  ahi[kk] + 16384 + cb);
            acc[0][0] = __builtin_amdgcn_mfma_f32_32x32x16_bf16(a0, b0, acc[0][0], 0, 0, 0);
            acc[1][0] = __builtin_amdgcn_mfma_f32_32x32x16_bf16(a1, b0, acc[1][0], 0, 0, 0);
            acc[0][1] = __builtin_amdgcn_mfma_f32_32x32x16_bf16(a0, b1, acc[0][1], 0, 0, 0);
            acc[1][1] = __builtin_amdgcn_mfma_f32_32x32x16_bf16(a1, b1, acc[1][1], 0, 0, 0);
        }
    }
    __builtin_amdgcn_s_setprio(0);

    __syncthreads();   // all waves done READING act
    #pragma unroll
    for (int tr = 0; tr < 2; ++tr) {
        unsigned char* rowp = actL + (rbase + tr * 32 + l31) * 512;
        #pragma unroll
        for (int tn = 0; tn < 2; ++tn) {
            #pragma unroll
            for (int g4 = 0; g4 < 4; ++g4) {
                float v0 = fmaxf(acc[tn][tr][g4 * 4 + 0], 0.f);
                float v1 = fmaxf(acc[tn][tr][g4 * 4 + 1], 0.f);
                float v2 = fmaxf(acc[tn][tr][g4 * 4 + 2], 0.f);
                float v3 = fmaxf(acc[tn][tr][g4 * 4 + 3], 0.f);
                int n0b = (nblk + tn * 32 + g4 * 8 + hi * 4) * 2;
                uint2 u; u.x = cvt_pk_bf16(v0, v1); u.y = cvt_pk_bf16(v2, v3);
                *(uint2*)(rowp + (n0b ^ rswz)) = u;
            }
        }
    }
    __syncthreads();   // act ready for next layer
}

// ---------------------------------------------------------------------------
// fused MLP: enc -> 7x(GEMM+bias+relu), act in LDS, weights global->reg
// 8 waves x (64n x 64r), 2 blocks/CU -> 4 waves/SIMD (R2-proven reg fit)
// ---------------------------------------------------------------------------
__global__ __launch_bounds__(THREADS, 4)
void nerf_main(const float* __restrict__ x,
               const float* __restrict__ b_in,
               const float* __restrict__ b_hid,
               const float* __restrict__ b_out,
               const unsigned char* __restrict__ ws,
               float* __restrict__ out, long ntot) {
    __shared__ __align__(16) unsigned char actL[65536];  // bf16 [128][256]

    const int tid  = threadIdx.x;
    const int lane = tid & 63;
    const int wv   = tid >> 6;            // 0..7
    const int ng   = wv & 3;
    const int rg   = wv >> 2;
    const int l31  = lane & 31;
    const int hi   = lane >> 5;
    const int hi16 = hi << 4;
    const int rswz  = (l31 & 15) << 3;    // 8B-granular act swizzle
    const int rswz2 = rswz ^ 8;
    const int nblk  = ng * 64;
    const int rbase = rg * 64;
    const long gr0 = (long)blockIdx.x * BR;

    // ---- positional encoding (R2/R5-proven 512-thread body, one pass) ----
    {
        const int rr = tid >> 2, part = tid & 3;
        const int co = part >> 1, hf = part & 1;
        const long grow = gr0 + rr;
        float xv = (grow < ntot) ? x[grow * 2 + co] : 0.f;
        unsigned char* rowp = actL + rr * 512;
        const int rsw = (rr & 15) << 3;
        const int kb = co * 20 + hf * 10;
        float vv[10];
        #pragma unroll
        for (int f = 0; f < 10; ++f) {
            float ang = xv * (float)(1 << f);
            vv[f] = hf ? __cosf(ang) : __sinf(ang);
        }
        #pragma unroll
        for (int p = 0; p < 5; ++p) {
            unsigned int u = cvt_pk_bf16(vv[2 * p], vv[2 * p + 1]);
            int byte = (kb + 2 * p) * 2;
            *(unsigned int*)(rowp + (byte ^ rsw)) = u;
        }
        int z = 80 + part * 12;           // zero-pad bytes [80,128)
        *(unsigned int*)(rowp + ((z    ) ^ rsw)) = 0u;
        *(unsigned int*)(rowp + ((z + 4) ^ rsw)) = 0u;
        *(unsigned int*)(rowp + ((z + 8) ^ rsw)) = 0u;
    }
    __syncthreads();

    // precomputed swizzled B-read addresses (kills per-read VALU)
    const unsigned char* alo[4];
    const unsigned char* ahi[4];
    #pragma unroll
    for (int kk = 0; kk < 4; ++kk) {
        const int bo = kk * 32 + hi16;
        alo[kk] = actL + (rbase + l31) * 512 + (bo ^ rswz);
        ahi[kk] = actL + (rbase + l31) * 512 + (bo ^ rswz2);
    }

    f32x16 acc[2][2];
    const unsigned char* wstream = ws + ng * NG_STRIDE + lane * 16;

    // layer 0 (k=64, 1 chunk)
    layer_pass<1>(wstream, b_in, actL, acc, alo, ahi, nblk, rbase, l31, hi, rswz);
    wstream += 8192;

    // layers 1..6
    #pragma unroll 1
    for (int l = 0; l < 6; ++l) {
        layer_pass<4>(wstream, b_hid + l * 256,
                      actL, acc, alo, ahi, nblk, rbase, l31, hi, rswz);
        wstream += 32768;
    }

    // ---- layer 7: [128][256] @ Wt_out[32pad][256] -> tanh/100 -> out ----
    if (wv < 4) {
        f32x16 c0, c1;
        #pragma unroll
        for (int j = 0; j < 16; ++j) { c0[j] = 0.f; c1[j] = 0.f; }
        const unsigned char* wo   = ws + WS_WOUT + lane * 16;
        const unsigned char* arow = actL + (wv * 32 + l31) * 512;
        #pragma unroll
        for (int kk = 0; kk < 16; ++kk) {
            bf16x8 a = *(const bf16x8*)(wo + kk * 1024);
            const int bo = kk * 32 + hi16;
            bf16x8 b = ld_act(arow + (bo ^ rswz), arow + (bo ^ rswz2));
            if (kk & 1) c1 = __builtin_amdgcn_mfma_f32_32x32x16_bf16(a, b, c1, 0, 0, 0);
            else        c0 = __builtin_amdgcn_mfma_f32_32x32x16_bf16(a, b, c0, 0, 0, 0);
        }
        if (hi == 0) {
            long row = gr0 + wv * 32 + l31;
            if (row < ntot) {
                float* op = out + row * 3;
                #pragma unroll
                for (int j = 0; j < 3; ++j)
                    op[j] = tanhf(c0[j] + c1[j] + b_out[j]) * 0.01f;
            }
        }
    }
}

extern "C" void kernel_launch(void* const* d_in, const int* in_sizes, int n_in,
                              void* d_out, int out_size, void* d_ws, size_t ws_size,
                              hipStream_t stream) {
    (void)n_in; (void)out_size;
    const float* x     = (const float*)d_in[0];
    const float* W_in  = (const float*)d_in[1];
    const float* b_in  = (const float*)d_in[2];
    const float* W_hid = (const float*)d_in[3];
    const float* b_hid = (const float*)d_in[4];
    const float* W_out = (const float*)d_in[5];
    const float* b_out = (const float*)d_in[6];
    unsigned char* ws  = (unsigned char*)d_ws;
    float* out = (float*)d_out;

    if (ws_size < (size_t)WS_TOTAL) return;

    const long ntot = (long)in_sizes[0] / 2;          // total points
    const int  grid = (int)((ntot + BR - 1) / BR);

    prep_kernel<<<1632, 256, 0, stream>>>(W_in, W_hid, W_out, ws);
    nerf_main<<<grid, THREADS, 0, stream>>>(x, b_in, b_hid, b_out, ws, out, ntot);
}